// Round 5
// baseline (1033.674 us; speedup 1.0000x reference)
//
#include <hip/hip_runtime.h>

#define N_NODES 100000
#define N_EDGES 1600000
#define N_GRAPHS 64

// ---------------- CSR build ----------------

__global__ __launch_bounds__(256) void k_zero_int(int* __restrict__ p, int n) {
  int i = blockIdx.x * 256 + threadIdx.x;
  if (i < n) p[i] = 0;
}

__global__ __launch_bounds__(256) void k_hist(const int* __restrict__ ei, int* __restrict__ deg) {
  int e = blockIdx.x * 256 + threadIdx.x;
  if (e < N_EDGES) atomicAdd(&deg[ei[N_EDGES + e]], 1);
}

// exclusive scan within 256-blocks, emit block sums
__global__ __launch_bounds__(256) void k_scan1(const int* __restrict__ deg, int* __restrict__ part,
                                               int* __restrict__ bsum) {
  __shared__ int tmp[256];
  int i = blockIdx.x * 256 + threadIdx.x;
  int v = (i < N_NODES) ? deg[i] : 0;
  tmp[threadIdx.x] = v;
  __syncthreads();
  for (int o = 1; o < 256; o <<= 1) {
    int t = (threadIdx.x >= o) ? tmp[threadIdx.x - o] : 0;
    __syncthreads();
    tmp[threadIdx.x] += t;
    __syncthreads();
  }
  if (i < N_NODES) part[i] = tmp[threadIdx.x] - v;  // exclusive
  if (threadIdx.x == 255) bsum[blockIdx.x] = tmp[255];
}

__global__ __launch_bounds__(512) void k_scan2(const int* __restrict__ bsum, int* __restrict__ boff, int nb) {
  __shared__ int tmp[512];
  int v = ((int)threadIdx.x < nb) ? bsum[threadIdx.x] : 0;
  tmp[threadIdx.x] = v;
  __syncthreads();
  for (int o = 1; o < 512; o <<= 1) {
    int t = (threadIdx.x >= o) ? tmp[threadIdx.x - o] : 0;
    __syncthreads();
    tmp[threadIdx.x] += t;
    __syncthreads();
  }
  if ((int)threadIdx.x < nb) boff[threadIdx.x] = tmp[threadIdx.x] - v;  // exclusive
}

__global__ __launch_bounds__(256) void k_scan3(const int* __restrict__ part, const int* __restrict__ boff,
                                               int* __restrict__ rowptr, int* __restrict__ cursor) {
  int i = blockIdx.x * 256 + threadIdx.x;
  if (i < N_NODES) {
    int r = part[i] + boff[i >> 8];
    rowptr[i] = r;
    cursor[i] = r;
  } else if (i == N_NODES) {
    rowptr[N_NODES] = N_EDGES;
  }
}

__global__ __launch_bounds__(256) void k_fill(const int* __restrict__ ei, int* __restrict__ cursor,
                                              int* __restrict__ csr) {
  int e = blockIdx.x * 256 + threadIdx.x;
  if (e < N_EDGES) {
    int d = ei[N_EDGES + e];
    int p = atomicAdd(&cursor[d], 1);
    csr[p] = ei[e];
  }
}

// ---------------- Layer 1 (IN_CH=4) ----------------

__global__ __launch_bounds__(256) void k_l1_agg(const float* __restrict__ x, const int* __restrict__ rowptr,
                                                const int* __restrict__ csr, float* __restrict__ agg4) {
  int t = blockIdx.x * 256 + threadIdx.x;
  if (t >= N_NODES * 4) return;
  int node = t >> 2, c = t & 3;
  int s = rowptr[node], e = rowptr[node + 1];
  float a = 0.f;
  for (int p = s; p < e; ++p) a += x[(size_t)csr[p] * 4 + c];
  agg4[t] = a;
}

__global__ __launch_bounds__(256) void k_l1_comb(const float* __restrict__ x, const float* __restrict__ agg4,
                                                 const float* __restrict__ w_rel, const float* __restrict__ b_rel,
                                                 const float* __restrict__ w_root, float* __restrict__ out) {
  int t = blockIdx.x * 256 + threadIdx.x;
  int node = t >> 7, c = t & 127;
  if (node >= N_NODES) return;
  float acc = b_rel[c];
#pragma unroll
  for (int k = 0; k < 4; ++k) acc += agg4[node * 4 + k] * w_rel[k * 128 + c];
#pragma unroll
  for (int k = 0; k < 4; ++k) acc += x[node * 4 + k] * w_root[k * 128 + c];
  out[(size_t)node * 128 + c] = fmaxf(acc, 0.f);
}

// ---------------- Layers 2-4: pure gather-sum ----------------
// 32 lanes per dst row (float4/lane = 512B/row coalesced), 2 nodes per wave,
// 4-deep edge unroll => 4 float4 loads in flight per half-wave.
__global__ __launch_bounds__(256) void k_agg3(const float* __restrict__ h, const int* __restrict__ rowptr,
                                              const int* __restrict__ csr, float* __restrict__ aggout) {
  int node = (blockIdx.x * 256 + threadIdx.x) >> 5;
  int l = threadIdx.x & 31;
  if (node >= N_NODES) return;
  int s = rowptr[node], e = rowptr[node + 1];
  float4 acc = make_float4(0.f, 0.f, 0.f, 0.f);
  int p = s;
  for (; p + 4 <= e; p += 4) {
    int s0 = csr[p], s1 = csr[p + 1], s2 = csr[p + 2], s3 = csr[p + 3];
    float4 v0 = *(const float4*)&h[(size_t)s0 * 128 + l * 4];
    float4 v1 = *(const float4*)&h[(size_t)s1 * 128 + l * 4];
    float4 v2 = *(const float4*)&h[(size_t)s2 * 128 + l * 4];
    float4 v3 = *(const float4*)&h[(size_t)s3 * 128 + l * 4];
    acc.x += v0.x + v1.x + v2.x + v3.x;
    acc.y += v0.y + v1.y + v2.y + v3.y;
    acc.z += v0.z + v1.z + v2.z + v3.z;
    acc.w += v0.w + v1.w + v2.w + v3.w;
  }
  for (; p < e; ++p) {
    int s0 = csr[p];
    float4 v = *(const float4*)&h[(size_t)s0 * 128 + l * 4];
    acc.x += v.x;
    acc.y += v.y;
    acc.z += v.z;
    acc.w += v.w;
  }
  *(float4*)&aggout[(size_t)node * 128 + l * 4] = acc;
}

// ---------------- Layers 2-4: fused dual GEMM + bias + ReLU ----------------
// out = relu(agg @ w_rel + h @ w_root + bias). 128x128 tile, 256 threads,
// 8x8 per thread, K-chunk 32. LDS 32.0 KB (no pad needed: a-reads are
// 16-lane broadcasts across 16 banks; b-reads 2-way aliased = free).
// ALL inner-loop math via explicit .xyzw components: no address-taken
// locals, no runtime-indexed arrays (round-4 spill root cause).
#define GEMM_STEP(AV, M)                                                                   \
  acc[M][0].x += (AV)*b0.x; acc[M][0].y += (AV)*b0.y;                                      \
  acc[M][0].z += (AV)*b0.z; acc[M][0].w += (AV)*b0.w;                                      \
  acc[M][1].x += (AV)*b1.x; acc[M][1].y += (AV)*b1.y;                                      \
  acc[M][1].z += (AV)*b1.z; acc[M][1].w += (AV)*b1.w;

__global__ __launch_bounds__(256) void k_gemm4(const float* __restrict__ agg, const float* __restrict__ h,
                                               const float* __restrict__ w_rel, const float* __restrict__ w_root,
                                               const float* __restrict__ bias, float* __restrict__ out) {
  __shared__ float AsT[32][128];
  __shared__ float Bs[32][128];
  const int n0 = blockIdx.x * 128;
  const int tid = threadIdx.x;
  const int tr = tid >> 4;  // 0..15 -> rows tr*8..tr*8+7
  const int tc = tid & 15;  // 0..15 -> cols 4tc..4tc+3, 64+4tc..64+4tc+3
  float4 acc[8][2];
#pragma unroll
  for (int m = 0; m < 8; ++m) {
    acc[m][0] = make_float4(0.f, 0.f, 0.f, 0.f);
    acc[m][1] = make_float4(0.f, 0.f, 0.f, 0.f);
  }

  for (int chunk = 0; chunk < 2; ++chunk) {
    const float* src = (chunk == 0) ? agg : h;
    const float* wgt = (chunk == 0) ? w_rel : w_root;
    for (int k0 = 0; k0 < 128; k0 += 32) {
      // stage A transposed: 128 rows x 32 k (1024 float4s, 4 per thread)
#pragma unroll
      for (int t = 0; t < 4; ++t) {
        int idx = tid + t * 256;
        int r = idx & 127, q = idx >> 7;  // q = 0..7
        int gr = n0 + r;
        if (gr >= N_NODES) gr = N_NODES - 1;
        float4 v = *(const float4*)&src[(size_t)gr * 128 + k0 + q * 4];
        AsT[q * 4 + 0][r] = v.x;
        AsT[q * 4 + 1][r] = v.y;
        AsT[q * 4 + 2][r] = v.z;
        AsT[q * 4 + 3][r] = v.w;
      }
      // stage B: 32 k x 128 c
#pragma unroll
      for (int t = 0; t < 4; ++t) {
        int idx = tid + t * 256;
        int k = idx >> 5, cq = idx & 31;
        *(float4*)&Bs[k][cq * 4] = *(const float4*)&wgt[(size_t)(k0 + k) * 128 + cq * 4];
      }
      __syncthreads();
#pragma unroll 4
      for (int k = 0; k < 32; ++k) {
        float4 a0 = *(float4*)&AsT[k][tr * 8];
        float4 a1 = *(float4*)&AsT[k][tr * 8 + 4];
        float4 b0 = *(float4*)&Bs[k][tc * 4];
        float4 b1 = *(float4*)&Bs[k][tc * 4 + 64];
        GEMM_STEP(a0.x, 0)
        GEMM_STEP(a0.y, 1)
        GEMM_STEP(a0.z, 2)
        GEMM_STEP(a0.w, 3)
        GEMM_STEP(a1.x, 4)
        GEMM_STEP(a1.y, 5)
        GEMM_STEP(a1.z, 6)
        GEMM_STEP(a1.w, 7)
      }
      __syncthreads();
    }
  }

  float4 bi0 = *(const float4*)&bias[tc * 4];
  float4 bi1 = *(const float4*)&bias[tc * 4 + 64];
#pragma unroll
  for (int m = 0; m < 8; ++m) {
    int row = n0 + tr * 8 + m;
    if (row < N_NODES) {
      float4 o0, o1;
      o0.x = fmaxf(acc[m][0].x + bi0.x, 0.f);
      o0.y = fmaxf(acc[m][0].y + bi0.y, 0.f);
      o0.z = fmaxf(acc[m][0].z + bi0.z, 0.f);
      o0.w = fmaxf(acc[m][0].w + bi0.w, 0.f);
      o1.x = fmaxf(acc[m][1].x + bi1.x, 0.f);
      o1.y = fmaxf(acc[m][1].y + bi1.y, 0.f);
      o1.z = fmaxf(acc[m][1].z + bi1.z, 0.f);
      o1.w = fmaxf(acc[m][1].w + bi1.w, 0.f);
      *(float4*)&out[(size_t)row * 128 + tc * 4] = o0;
      *(float4*)&out[(size_t)row * 128 + tc * 4 + 64] = o1;
    }
  }
}

// ---------------- Pooling ----------------

__device__ __forceinline__ int lower_bound_batch(const int* __restrict__ batch, int key) {
  int lo = 0, hi = N_NODES;
  while (lo < hi) {
    int mid = (lo + hi) >> 1;
    if (batch[mid] < key) lo = mid + 1;
    else hi = mid;
  }
  return lo;
}

__global__ __launch_bounds__(256) void k_pool1(const float* __restrict__ h, const int* __restrict__ batch,
                                               float* __restrict__ psum, float* __restrict__ pmax) {
  int b = blockIdx.x;
  int g = b >> 2, q = b & 3;
  int start = lower_bound_batch(batch, g);
  int end = lower_bound_batch(batch, g + 1);
  int c = threadIdx.x & 127;
  int half = threadIdx.x >> 7;
  float sum = 0.f, mx = -3.0e38f;
  for (int n = start + q * 2 + half; n < end; n += 8) {
    float v = h[(size_t)n * 128 + c];
    sum += v;
    mx = fmaxf(mx, v);
  }
  __shared__ float ss[128], sm[128];
  if (half == 0) { ss[c] = sum; sm[c] = mx; }
  __syncthreads();
  if (half == 1) { ss[c] += sum; sm[c] = fmaxf(sm[c], mx); }
  __syncthreads();
  if (half == 0) {
    psum[(size_t)b * 128 + c] = ss[c];
    pmax[(size_t)b * 128 + c] = sm[c];
  }
}

__global__ __launch_bounds__(128) void k_pool2(const float* __restrict__ psum, const float* __restrict__ pmax,
                                               const int* __restrict__ batch, float* __restrict__ pooled) {
  int g = blockIdx.x;
  int c = threadIdx.x;
  int start = lower_bound_batch(batch, g), end = lower_bound_batch(batch, g + 1);
  int count = end - start;
  float s = 0.f, m = -3.0e38f;
#pragma unroll
  for (int q = 0; q < 4; ++q) {
    s += psum[(size_t)(g * 4 + q) * 128 + c];
    m = fmaxf(m, pmax[(size_t)(g * 4 + q) * 128 + c]);
  }
  pooled[(size_t)g * 256 + c] = (count > 0) ? m : 0.f;
  pooled[(size_t)g * 256 + 128 + c] = s / fmaxf((float)count, 1.f);
}

// ---------------- Final FC (fused metadata branch) ----------------

__global__ __launch_bounds__(128) void k_fc(const float* __restrict__ pooled, const float* __restrict__ metadata,
                                            const float* __restrict__ convm_w, const float* __restrict__ convm_b,
                                            const float* __restrict__ fc_w, const float* __restrict__ fc_b,
                                            const float* __restrict__ fc2_w, const float* __restrict__ fc2_b,
                                            float* __restrict__ out) {
  int g = blockIdx.x;
  int tid = threadIdx.x;
  __shared__ float xc[260];
  xc[tid] = pooled[(size_t)g * 256 + tid];
  xc[128 + tid] = pooled[(size_t)g * 256 + 128 + tid];
  if (tid < 4) xc[256 + tid] = fmaxf(metadata[g] * convm_w[tid] + convm_b[tid], 0.f);
  __syncthreads();
  float acc = fc_b[tid];
  for (int k = 0; k < 260; ++k) acc += xc[k] * fc_w[(size_t)k * 128 + tid];
  float partial = fmaxf(acc, 0.f) * fc2_w[tid];
#pragma unroll
  for (int off = 32; off > 0; off >>= 1) partial += __shfl_down(partial, off);
  __shared__ float wred[2];
  if ((tid & 63) == 0) wred[tid >> 6] = partial;
  __syncthreads();
  if (tid == 0) out[g] = wred[0] + wred[1] + fc2_b[0];
}

// ---------------- launch ----------------

extern "C" void kernel_launch(void* const* d_in, const int* in_sizes, int n_in,
                              void* d_out, int out_size, void* d_ws, size_t ws_size,
                              hipStream_t stream) {
  const float* x = (const float*)d_in[0];
  const float* metadata = (const float*)d_in[1];
  const int* ei = (const int*)d_in[2];
  const int* batch = (const int*)d_in[3];
  const float* w_rel[4] = {(const float*)d_in[4], (const float*)d_in[7], (const float*)d_in[10], (const float*)d_in[13]};
  const float* b_rel[4] = {(const float*)d_in[5], (const float*)d_in[8], (const float*)d_in[11], (const float*)d_in[14]};
  const float* w_root[4] = {(const float*)d_in[6], (const float*)d_in[9], (const float*)d_in[12], (const float*)d_in[15]};
  const float* convm_w = (const float*)d_in[16];
  const float* convm_b = (const float*)d_in[17];
  const float* fc_w = (const float*)d_in[18];
  const float* fc_b = (const float*)d_in[19];
  const float* fc2_w = (const float*)d_in[20];
  const float* fc2_b = (const float*)d_in[21];
  float* out = (float*)d_out;

  char* ws = (char*)d_ws;
  size_t off = 0;
  auto alloc = [&](size_t bytes) {
    off = (off + 255) & ~(size_t)255;
    void* p = ws + off;
    off += bytes;
    return p;
  };
  int* deg = (int*)alloc((size_t)N_NODES * 4);
  int* rowptr = (int*)alloc((size_t)(N_NODES + 1) * 4);
  int* cursor = (int*)alloc((size_t)N_NODES * 4);
  int* bsum = (int*)alloc(512 * 4);
  int* boff = (int*)alloc(512 * 4);
  int* csr = (int*)alloc((size_t)N_EDGES * 4);
  float* agg4 = (float*)alloc((size_t)N_NODES * 4 * 4);
  float* bufA = (float*)alloc((size_t)N_NODES * 128 * 4);  // h (in-place updated)
  float* bufB = (float*)alloc((size_t)N_NODES * 128 * 4);  // agg scratch
  float* psum = (float*)alloc((size_t)256 * 128 * 4);
  float* pmax = (float*)alloc((size_t)256 * 128 * 4);
  float* pooled = (float*)alloc((size_t)64 * 256 * 4);

  const int nblk_nodes = (N_NODES + 255) / 256;
  const int nblk_edges = (N_EDGES + 255) / 256;

  // CSR build
  k_zero_int<<<nblk_nodes, 256, 0, stream>>>(deg, N_NODES);
  k_hist<<<nblk_edges, 256, 0, stream>>>(ei, deg);
  k_scan1<<<nblk_nodes, 256, 0, stream>>>(deg, rowptr, bsum);
  k_scan2<<<1, 512, 0, stream>>>(bsum, boff, nblk_nodes);
  k_scan3<<<(N_NODES + 1 + 255) / 256, 256, 0, stream>>>(rowptr, boff, rowptr, cursor);
  k_fill<<<nblk_edges, 256, 0, stream>>>(ei, cursor, csr);

  // Layer 1
  k_l1_agg<<<(N_NODES * 4 + 255) / 256, 256, 0, stream>>>(x, rowptr, csr, agg4);
  k_l1_comb<<<(N_NODES * 128 + 255) / 256, 256, 0, stream>>>(x, agg4, w_rel[0], b_rel[0], w_root[0], bufA);

  // Layers 2-4: agg (bufA -> bufB), fused GEMM (bufB,bufA -> bufA in-place)
  for (int l = 1; l < 4; ++l) {
    k_agg3<<<(N_NODES * 32 + 255) / 256, 256, 0, stream>>>(bufA, rowptr, csr, bufB);
    k_gemm4<<<(N_NODES + 127) / 128, 256, 0, stream>>>(bufB, bufA, w_rel[l], w_root[l], b_rel[l], bufA);
  }

  // Pool + FC
  k_pool1<<<256, 256, 0, stream>>>(bufA, batch, psum, pmax);
  k_pool2<<<64, 128, 0, stream>>>(psum, pmax, batch, pooled);
  k_fc<<<64, 128, 0, stream>>>(pooled, metadata, convm_w, convm_b, fc_w, fc_b, fc2_w, fc2_b, out);
}

// Round 6
// 992.220 us; speedup vs baseline: 1.0418x; 1.0418x over previous
//
#include <hip/hip_runtime.h>

#define N_NODES 100000
#define N_EDGES 1600000
#define N_GRAPHS 64

// ---------------- CSR build ----------------

__global__ __launch_bounds__(256) void k_zero_int(int* __restrict__ p, int n) {
  int i = blockIdx.x * 256 + threadIdx.x;
  if (i < n) p[i] = 0;
}

__global__ __launch_bounds__(256) void k_hist(const int* __restrict__ ei, int* __restrict__ deg) {
  int e = blockIdx.x * 256 + threadIdx.x;
  if (e < N_EDGES) atomicAdd(&deg[ei[N_EDGES + e]], 1);
}

// exclusive scan within 256-blocks, emit block sums
__global__ __launch_bounds__(256) void k_scan1(const int* __restrict__ deg, int* __restrict__ part,
                                               int* __restrict__ bsum) {
  __shared__ int tmp[256];
  int i = blockIdx.x * 256 + threadIdx.x;
  int v = (i < N_NODES) ? deg[i] : 0;
  tmp[threadIdx.x] = v;
  __syncthreads();
  for (int o = 1; o < 256; o <<= 1) {
    int t = (threadIdx.x >= o) ? tmp[threadIdx.x - o] : 0;
    __syncthreads();
    tmp[threadIdx.x] += t;
    __syncthreads();
  }
  if (i < N_NODES) part[i] = tmp[threadIdx.x] - v;  // exclusive
  if (threadIdx.x == 255) bsum[blockIdx.x] = tmp[255];
}

__global__ __launch_bounds__(512) void k_scan2(const int* __restrict__ bsum, int* __restrict__ boff, int nb) {
  __shared__ int tmp[512];
  int v = ((int)threadIdx.x < nb) ? bsum[threadIdx.x] : 0;
  tmp[threadIdx.x] = v;
  __syncthreads();
  for (int o = 1; o < 512; o <<= 1) {
    int t = (threadIdx.x >= o) ? tmp[threadIdx.x - o] : 0;
    __syncthreads();
    tmp[threadIdx.x] += t;
    __syncthreads();
  }
  if ((int)threadIdx.x < nb) boff[threadIdx.x] = tmp[threadIdx.x] - v;  // exclusive
}

__global__ __launch_bounds__(256) void k_scan3(const int* __restrict__ part, const int* __restrict__ boff,
                                               int* __restrict__ rowptr, int* __restrict__ cursor) {
  int i = blockIdx.x * 256 + threadIdx.x;
  if (i < N_NODES) {
    int r = part[i] + boff[i >> 8];
    rowptr[i] = r;
    cursor[i] = r;
  } else if (i == N_NODES) {
    rowptr[N_NODES] = N_EDGES;
  }
}

// XCD-partitioned windowed fill: window w (12500 nodes) handled only by
// blocks with bid&7==w -> (round-robin dispatch) one XCD per window. The
// ~800KB csr window + cursor slice stay in that XCD's L2, so the ~16
// random 4B writes per 64B line coalesce in-cache before writeback
// (vs 16x full-line HBM amplification in the flat version). Partitioning
// is performance-only; atomics keep it correct under any dispatch map.
#define FW_NPW 12500   // nodes per window (8 windows)
#define FW_EPS 12500   // edges per slice (128 slices)
__global__ __launch_bounds__(256) void k_fill_win(const int* __restrict__ ei, int* __restrict__ cursor,
                                                  int* __restrict__ csr) {
  int bid = blockIdx.x;
  int w = bid & 7;
  int s = bid >> 3;
  int lo = w * FW_NPW, hi = lo + FW_NPW;
  int e0 = s * FW_EPS, e1 = e0 + FW_EPS;
  for (int e = e0 + threadIdx.x; e < e1; e += 256) {
    int d = ei[N_EDGES + e];
    if (d >= lo && d < hi) {
      int p = atomicAdd(&cursor[d], 1);
      csr[p] = ei[e];
    }
  }
}

// ---------------- Layer 1 (IN_CH=4) ----------------

__global__ __launch_bounds__(256) void k_l1_agg(const float* __restrict__ x, const int* __restrict__ rowptr,
                                                const int* __restrict__ csr, float* __restrict__ agg4) {
  int t = blockIdx.x * 256 + threadIdx.x;
  if (t >= N_NODES * 4) return;
  int node = t >> 2, c = t & 3;
  int s = rowptr[node], e = rowptr[node + 1];
  float a = 0.f;
  for (int p = s; p < e; ++p) a += x[(size_t)csr[p] * 4 + c];
  agg4[t] = a;
}

__global__ __launch_bounds__(256) void k_l1_comb(const float* __restrict__ x, const float* __restrict__ agg4,
                                                 const float* __restrict__ w_rel, const float* __restrict__ b_rel,
                                                 const float* __restrict__ w_root, float* __restrict__ out) {
  int t = blockIdx.x * 256 + threadIdx.x;
  int node = t >> 7, c = t & 127;
  if (node >= N_NODES) return;
  float acc = b_rel[c];
#pragma unroll
  for (int k = 0; k < 4; ++k) acc += agg4[node * 4 + k] * w_rel[k * 128 + c];
#pragma unroll
  for (int k = 0; k < 4; ++k) acc += x[node * 4 + k] * w_root[k * 128 + c];
  out[(size_t)node * 128 + c] = fmaxf(acc, 0.f);
}

// ---------------- Layers 2-4: pure gather-sum ----------------
// 32 lanes per dst row (float4/lane = 512B/row coalesced), unroll 8:
// 8 float4 (128B) outstanding per lane for L3-latency hiding.
__global__ __launch_bounds__(256) void k_agg4(const float* __restrict__ h, const int* __restrict__ rowptr,
                                              const int* __restrict__ csr, float* __restrict__ aggout) {
  int node = (blockIdx.x * 256 + threadIdx.x) >> 5;
  int l = threadIdx.x & 31;
  if (node >= N_NODES) return;
  int s = rowptr[node], e = rowptr[node + 1];
  float4 acc = make_float4(0.f, 0.f, 0.f, 0.f);
  int p = s;
  for (; p + 8 <= e; p += 8) {
    int s0 = csr[p], s1 = csr[p + 1], s2 = csr[p + 2], s3 = csr[p + 3];
    int s4 = csr[p + 4], s5 = csr[p + 5], s6 = csr[p + 6], s7 = csr[p + 7];
    float4 v0 = *(const float4*)&h[(size_t)s0 * 128 + l * 4];
    float4 v1 = *(const float4*)&h[(size_t)s1 * 128 + l * 4];
    float4 v2 = *(const float4*)&h[(size_t)s2 * 128 + l * 4];
    float4 v3 = *(const float4*)&h[(size_t)s3 * 128 + l * 4];
    float4 v4 = *(const float4*)&h[(size_t)s4 * 128 + l * 4];
    float4 v5 = *(const float4*)&h[(size_t)s5 * 128 + l * 4];
    float4 v6 = *(const float4*)&h[(size_t)s6 * 128 + l * 4];
    float4 v7 = *(const float4*)&h[(size_t)s7 * 128 + l * 4];
    acc.x += (v0.x + v1.x) + (v2.x + v3.x) + ((v4.x + v5.x) + (v6.x + v7.x));
    acc.y += (v0.y + v1.y) + (v2.y + v3.y) + ((v4.y + v5.y) + (v6.y + v7.y));
    acc.z += (v0.z + v1.z) + (v2.z + v3.z) + ((v4.z + v5.z) + (v6.z + v7.z));
    acc.w += (v0.w + v1.w) + (v2.w + v3.w) + ((v4.w + v5.w) + (v6.w + v7.w));
  }
  for (; p + 4 <= e; p += 4) {
    int s0 = csr[p], s1 = csr[p + 1], s2 = csr[p + 2], s3 = csr[p + 3];
    float4 v0 = *(const float4*)&h[(size_t)s0 * 128 + l * 4];
    float4 v1 = *(const float4*)&h[(size_t)s1 * 128 + l * 4];
    float4 v2 = *(const float4*)&h[(size_t)s2 * 128 + l * 4];
    float4 v3 = *(const float4*)&h[(size_t)s3 * 128 + l * 4];
    acc.x += (v0.x + v1.x) + (v2.x + v3.x);
    acc.y += (v0.y + v1.y) + (v2.y + v3.y);
    acc.z += (v0.z + v1.z) + (v2.z + v3.z);
    acc.w += (v0.w + v1.w) + (v2.w + v3.w);
  }
  for (; p < e; ++p) {
    int s0 = csr[p];
    float4 v = *(const float4*)&h[(size_t)s0 * 128 + l * 4];
    acc.x += v.x;
    acc.y += v.y;
    acc.z += v.z;
    acc.w += v.w;
  }
  *(float4*)&aggout[(size_t)node * 128 + l * 4] = acc;
}

// ---------------- Layers 2-4: fused dual GEMM + bias + ReLU ----------------
// out = relu(agg @ w_rel + h @ w_root + bias). 128x128 tile, 256 threads,
// 8x8 per thread, K-chunk 32. LDS 32.0 KB. All inner-loop math via explicit
// .xyzw components: no address-taken locals, no runtime-indexed arrays.
#define GEMM_STEP(AV, M)                                                                   \
  acc[M][0].x += (AV)*b0.x; acc[M][0].y += (AV)*b0.y;                                      \
  acc[M][0].z += (AV)*b0.z; acc[M][0].w += (AV)*b0.w;                                      \
  acc[M][1].x += (AV)*b1.x; acc[M][1].y += (AV)*b1.y;                                      \
  acc[M][1].z += (AV)*b1.z; acc[M][1].w += (AV)*b1.w;

__global__ __launch_bounds__(256) void k_gemm4(const float* __restrict__ agg, const float* __restrict__ h,
                                               const float* __restrict__ w_rel, const float* __restrict__ w_root,
                                               const float* __restrict__ bias, float* __restrict__ out) {
  __shared__ float AsT[32][128];
  __shared__ float Bs[32][128];
  const int n0 = blockIdx.x * 128;
  const int tid = threadIdx.x;
  const int tr = tid >> 4;  // 0..15 -> rows tr*8..tr*8+7
  const int tc = tid & 15;  // 0..15 -> cols 4tc..4tc+3, 64+4tc..64+4tc+3
  float4 acc[8][2];
#pragma unroll
  for (int m = 0; m < 8; ++m) {
    acc[m][0] = make_float4(0.f, 0.f, 0.f, 0.f);
    acc[m][1] = make_float4(0.f, 0.f, 0.f, 0.f);
  }

  for (int chunk = 0; chunk < 2; ++chunk) {
    const float* src = (chunk == 0) ? agg : h;
    const float* wgt = (chunk == 0) ? w_rel : w_root;
    for (int k0 = 0; k0 < 128; k0 += 32) {
      // stage A transposed: 128 rows x 32 k (1024 float4s, 4 per thread)
#pragma unroll
      for (int t = 0; t < 4; ++t) {
        int idx = tid + t * 256;
        int r = idx & 127, q = idx >> 7;  // q = 0..7
        int gr = n0 + r;
        if (gr >= N_NODES) gr = N_NODES - 1;
        float4 v = *(const float4*)&src[(size_t)gr * 128 + k0 + q * 4];
        AsT[q * 4 + 0][r] = v.x;
        AsT[q * 4 + 1][r] = v.y;
        AsT[q * 4 + 2][r] = v.z;
        AsT[q * 4 + 3][r] = v.w;
      }
      // stage B: 32 k x 128 c
#pragma unroll
      for (int t = 0; t < 4; ++t) {
        int idx = tid + t * 256;
        int k = idx >> 5, cq = idx & 31;
        *(float4*)&Bs[k][cq * 4] = *(const float4*)&wgt[(size_t)(k0 + k) * 128 + cq * 4];
      }
      __syncthreads();
#pragma unroll 4
      for (int k = 0; k < 32; ++k) {
        float4 a0 = *(float4*)&AsT[k][tr * 8];
        float4 a1 = *(float4*)&AsT[k][tr * 8 + 4];
        float4 b0 = *(float4*)&Bs[k][tc * 4];
        float4 b1 = *(float4*)&Bs[k][tc * 4 + 64];
        GEMM_STEP(a0.x, 0)
        GEMM_STEP(a0.y, 1)
        GEMM_STEP(a0.z, 2)
        GEMM_STEP(a0.w, 3)
        GEMM_STEP(a1.x, 4)
        GEMM_STEP(a1.y, 5)
        GEMM_STEP(a1.z, 6)
        GEMM_STEP(a1.w, 7)
      }
      __syncthreads();
    }
  }

  float4 bi0 = *(const float4*)&bias[tc * 4];
  float4 bi1 = *(const float4*)&bias[tc * 4 + 64];
#pragma unroll
  for (int m = 0; m < 8; ++m) {
    int row = n0 + tr * 8 + m;
    if (row < N_NODES) {
      float4 o0, o1;
      o0.x = fmaxf(acc[m][0].x + bi0.x, 0.f);
      o0.y = fmaxf(acc[m][0].y + bi0.y, 0.f);
      o0.z = fmaxf(acc[m][0].z + bi0.z, 0.f);
      o0.w = fmaxf(acc[m][0].w + bi0.w, 0.f);
      o1.x = fmaxf(acc[m][1].x + bi1.x, 0.f);
      o1.y = fmaxf(acc[m][1].y + bi1.y, 0.f);
      o1.z = fmaxf(acc[m][1].z + bi1.z, 0.f);
      o1.w = fmaxf(acc[m][1].w + bi1.w, 0.f);
      *(float4*)&out[(size_t)row * 128 + tc * 4] = o0;
      *(float4*)&out[(size_t)row * 128 + tc * 4 + 64] = o1;
    }
  }
}

// ---------------- Pooling ----------------

__device__ __forceinline__ int lower_bound_batch(const int* __restrict__ batch, int key) {
  int lo = 0, hi = N_NODES;
  while (lo < hi) {
    int mid = (lo + hi) >> 1;
    if (batch[mid] < key) lo = mid + 1;
    else hi = mid;
  }
  return lo;
}

__global__ __launch_bounds__(256) void k_pool1(const float* __restrict__ h, const int* __restrict__ batch,
                                               float* __restrict__ psum, float* __restrict__ pmax) {
  int b = blockIdx.x;
  int g = b >> 2, q = b & 3;
  int start = lower_bound_batch(batch, g);
  int end = lower_bound_batch(batch, g + 1);
  int c = threadIdx.x & 127;
  int half = threadIdx.x >> 7;
  float sum = 0.f, mx = -3.0e38f;
  for (int n = start + q * 2 + half; n < end; n += 8) {
    float v = h[(size_t)n * 128 + c];
    sum += v;
    mx = fmaxf(mx, v);
  }
  __shared__ float ss[128], sm[128];
  if (half == 0) { ss[c] = sum; sm[c] = mx; }
  __syncthreads();
  if (half == 1) { ss[c] += sum; sm[c] = fmaxf(sm[c], mx); }
  __syncthreads();
  if (half == 0) {
    psum[(size_t)b * 128 + c] = ss[c];
    pmax[(size_t)b * 128 + c] = sm[c];
  }
}

__global__ __launch_bounds__(128) void k_pool2(const float* __restrict__ psum, const float* __restrict__ pmax,
                                               const int* __restrict__ batch, float* __restrict__ pooled) {
  int g = blockIdx.x;
  int c = threadIdx.x;
  int start = lower_bound_batch(batch, g), end = lower_bound_batch(batch, g + 1);
  int count = end - start;
  float s = 0.f, m = -3.0e38f;
#pragma unroll
  for (int q = 0; q < 4; ++q) {
    s += psum[(size_t)(g * 4 + q) * 128 + c];
    m = fmaxf(m, pmax[(size_t)(g * 4 + q) * 128 + c]);
  }
  pooled[(size_t)g * 256 + c] = (count > 0) ? m : 0.f;
  pooled[(size_t)g * 256 + 128 + c] = s / fmaxf((float)count, 1.f);
}

// ---------------- Final FC (fused metadata branch) ----------------

__global__ __launch_bounds__(128) void k_fc(const float* __restrict__ pooled, const float* __restrict__ metadata,
                                            const float* __restrict__ convm_w, const float* __restrict__ convm_b,
                                            const float* __restrict__ fc_w, const float* __restrict__ fc_b,
                                            const float* __restrict__ fc2_w, const float* __restrict__ fc2_b,
                                            float* __restrict__ out) {
  int g = blockIdx.x;
  int tid = threadIdx.x;
  __shared__ float xc[260];
  xc[tid] = pooled[(size_t)g * 256 + tid];
  xc[128 + tid] = pooled[(size_t)g * 256 + 128 + tid];
  if (tid < 4) xc[256 + tid] = fmaxf(metadata[g] * convm_w[tid] + convm_b[tid], 0.f);
  __syncthreads();
  float acc = fc_b[tid];
  for (int k = 0; k < 260; ++k) acc += xc[k] * fc_w[(size_t)k * 128 + tid];
  float partial = fmaxf(acc, 0.f) * fc2_w[tid];
#pragma unroll
  for (int off = 32; off > 0; off >>= 1) partial += __shfl_down(partial, off);
  __shared__ float wred[2];
  if ((tid & 63) == 0) wred[tid >> 6] = partial;
  __syncthreads();
  if (tid == 0) out[g] = wred[0] + wred[1] + fc2_b[0];
}

// ---------------- launch ----------------

extern "C" void kernel_launch(void* const* d_in, const int* in_sizes, int n_in,
                              void* d_out, int out_size, void* d_ws, size_t ws_size,
                              hipStream_t stream) {
  const float* x = (const float*)d_in[0];
  const float* metadata = (const float*)d_in[1];
  const int* ei = (const int*)d_in[2];
  const int* batch = (const int*)d_in[3];
  const float* w_rel[4] = {(const float*)d_in[4], (const float*)d_in[7], (const float*)d_in[10], (const float*)d_in[13]};
  const float* b_rel[4] = {(const float*)d_in[5], (const float*)d_in[8], (const float*)d_in[11], (const float*)d_in[14]};
  const float* w_root[4] = {(const float*)d_in[6], (const float*)d_in[9], (const float*)d_in[12], (const float*)d_in[15]};
  const float* convm_w = (const float*)d_in[16];
  const float* convm_b = (const float*)d_in[17];
  const float* fc_w = (const float*)d_in[18];
  const float* fc_b = (const float*)d_in[19];
  const float* fc2_w = (const float*)d_in[20];
  const float* fc2_b = (const float*)d_in[21];
  float* out = (float*)d_out;

  char* ws = (char*)d_ws;
  size_t off = 0;
  auto alloc = [&](size_t bytes) {
    off = (off + 255) & ~(size_t)255;
    void* p = ws + off;
    off += bytes;
    return p;
  };
  int* deg = (int*)alloc((size_t)N_NODES * 4);
  int* rowptr = (int*)alloc((size_t)(N_NODES + 1) * 4);
  int* cursor = (int*)alloc((size_t)N_NODES * 4);
  int* bsum = (int*)alloc(512 * 4);
  int* boff = (int*)alloc(512 * 4);
  int* csr = (int*)alloc((size_t)N_EDGES * 4);
  float* agg4 = (float*)alloc((size_t)N_NODES * 4 * 4);
  float* bufA = (float*)alloc((size_t)N_NODES * 128 * 4);  // h (in-place updated)
  float* bufB = (float*)alloc((size_t)N_NODES * 128 * 4);  // agg scratch
  float* psum = (float*)alloc((size_t)256 * 128 * 4);
  float* pmax = (float*)alloc((size_t)256 * 128 * 4);
  float* pooled = (float*)alloc((size_t)64 * 256 * 4);

  const int nblk_nodes = (N_NODES + 255) / 256;
  const int nblk_edges = (N_EDGES + 255) / 256;

  // CSR build
  k_zero_int<<<nblk_nodes, 256, 0, stream>>>(deg, N_NODES);
  k_hist<<<nblk_edges, 256, 0, stream>>>(ei, deg);
  k_scan1<<<nblk_nodes, 256, 0, stream>>>(deg, rowptr, bsum);
  k_scan2<<<1, 512, 0, stream>>>(bsum, boff, nblk_nodes);
  k_scan3<<<(N_NODES + 1 + 255) / 256, 256, 0, stream>>>(rowptr, boff, rowptr, cursor);
  k_fill_win<<<8 * 128, 256, 0, stream>>>(ei, cursor, csr);

  // Layer 1
  k_l1_agg<<<(N_NODES * 4 + 255) / 256, 256, 0, stream>>>(x, rowptr, csr, agg4);
  k_l1_comb<<<(N_NODES * 128 + 255) / 256, 256, 0, stream>>>(x, agg4, w_rel[0], b_rel[0], w_root[0], bufA);

  // Layers 2-4: agg (bufA -> bufB), fused GEMM (bufB,bufA -> bufA in-place)
  for (int l = 1; l < 4; ++l) {
    k_agg4<<<(N_NODES * 32 + 255) / 256, 256, 0, stream>>>(bufA, rowptr, csr, bufB);
    k_gemm4<<<(N_NODES + 127) / 128, 256, 0, stream>>>(bufB, bufA, w_rel[l], w_root[l], b_rel[l], bufA);
  }

  // Pool + FC
  k_pool1<<<256, 256, 0, stream>>>(bufA, batch, psum, pmax);
  k_pool2<<<64, 128, 0, stream>>>(psum, pmax, batch, pooled);
  k_fc<<<64, 128, 0, stream>>>(pooled, metadata, convm_w, convm_b, fc_w, fc_b, fc2_w, fc2_b, out);
}

// Round 7
// 872.238 us; speedup vs baseline: 1.1851x; 1.1376x over previous
//
#include <hip/hip_runtime.h>

#define N_NODES 100000
#define N_EDGES 1600000
#define N_GRAPHS 64

// fp32 -> bf16 with round-to-nearest-even
__device__ __forceinline__ unsigned int f2bf(float f) {
  unsigned int u = __float_as_uint(f);
  return (u + 0x7FFFu + ((u >> 16) & 1u)) >> 16;
}
#define BLO(u) __uint_as_float((u) << 16)
#define BHI(u) __uint_as_float((u) & 0xFFFF0000u)

// ---------------- CSR build ----------------

__global__ __launch_bounds__(256) void k_zero_int(int* __restrict__ p, int n) {
  int i = blockIdx.x * 256 + threadIdx.x;
  if (i < n) p[i] = 0;
}

__global__ __launch_bounds__(256) void k_hist(const int* __restrict__ ei, int* __restrict__ deg) {
  int e = blockIdx.x * 256 + threadIdx.x;
  if (e < N_EDGES) atomicAdd(&deg[ei[N_EDGES + e]], 1);
}

// exclusive scan within 256-blocks, emit block sums
__global__ __launch_bounds__(256) void k_scan1(const int* __restrict__ deg, int* __restrict__ part,
                                               int* __restrict__ bsum) {
  __shared__ int tmp[256];
  int i = blockIdx.x * 256 + threadIdx.x;
  int v = (i < N_NODES) ? deg[i] : 0;
  tmp[threadIdx.x] = v;
  __syncthreads();
  for (int o = 1; o < 256; o <<= 1) {
    int t = (threadIdx.x >= o) ? tmp[threadIdx.x - o] : 0;
    __syncthreads();
    tmp[threadIdx.x] += t;
    __syncthreads();
  }
  if (i < N_NODES) part[i] = tmp[threadIdx.x] - v;  // exclusive
  if (threadIdx.x == 255) bsum[blockIdx.x] = tmp[255];
}

__global__ __launch_bounds__(512) void k_scan2(const int* __restrict__ bsum, int* __restrict__ boff, int nb) {
  __shared__ int tmp[512];
  int v = ((int)threadIdx.x < nb) ? bsum[threadIdx.x] : 0;
  tmp[threadIdx.x] = v;
  __syncthreads();
  for (int o = 1; o < 512; o <<= 1) {
    int t = (threadIdx.x >= o) ? tmp[threadIdx.x - o] : 0;
    __syncthreads();
    tmp[threadIdx.x] += t;
    __syncthreads();
  }
  if ((int)threadIdx.x < nb) boff[threadIdx.x] = tmp[threadIdx.x] - v;  // exclusive
}

__global__ __launch_bounds__(256) void k_scan3(const int* __restrict__ part, const int* __restrict__ boff,
                                               int* __restrict__ rowptr, int* __restrict__ cursor) {
  int i = blockIdx.x * 256 + threadIdx.x;
  if (i < N_NODES) {
    int r = part[i] + boff[i >> 8];
    rowptr[i] = r;
    cursor[i] = r;
  } else if (i == N_NODES) {
    rowptr[N_NODES] = N_EDGES;
  }
}

// XCD-partitioned windowed fill (see round 6): window w handled by blocks
// with bid&7==w -> csr window + cursor slice stay L2-resident per XCD.
#define FW_NPW 12500   // nodes per window (8 windows)
#define FW_EPS 12500   // edges per slice (128 slices)
__global__ __launch_bounds__(256) void k_fill_win(const int* __restrict__ ei, int* __restrict__ cursor,
                                                  int* __restrict__ csr) {
  int bid = blockIdx.x;
  int w = bid & 7;
  int s = bid >> 3;
  int lo = w * FW_NPW, hi = lo + FW_NPW;
  int e0 = s * FW_EPS, e1 = e0 + FW_EPS;
  for (int e = e0 + threadIdx.x; e < e1; e += 256) {
    int d = ei[N_EDGES + e];
    if (d >= lo && d < hi) {
      int p = atomicAdd(&cursor[d], 1);
      csr[p] = ei[e];
    }
  }
}

// ---------------- Layer 1 (IN_CH=4) ----------------

__global__ __launch_bounds__(256) void k_l1_agg(const float* __restrict__ x, const int* __restrict__ rowptr,
                                                const int* __restrict__ csr, float* __restrict__ agg4) {
  int t = blockIdx.x * 256 + threadIdx.x;
  if (t >= N_NODES * 4) return;
  int node = t >> 2, c = t & 3;
  int s = rowptr[node], e = rowptr[node + 1];
  float a = 0.f;
  for (int p = s; p < e; ++p) a += x[(size_t)csr[p] * 4 + c];
  agg4[t] = a;
}

// emits fp32 h AND bf16 shadow copy (gather source for layer 2)
__global__ __launch_bounds__(256) void k_l1_comb(const float* __restrict__ x, const float* __restrict__ agg4,
                                                 const float* __restrict__ w_rel, const float* __restrict__ b_rel,
                                                 const float* __restrict__ w_root, float* __restrict__ out,
                                                 unsigned short* __restrict__ hb) {
  int t = blockIdx.x * 256 + threadIdx.x;
  int node = t >> 7, c = t & 127;
  if (node >= N_NODES) return;
  float acc = b_rel[c];
#pragma unroll
  for (int k = 0; k < 4; ++k) acc += agg4[node * 4 + k] * w_rel[k * 128 + c];
#pragma unroll
  for (int k = 0; k < 4; ++k) acc += x[node * 4 + k] * w_root[k * 128 + c];
  float r = fmaxf(acc, 0.f);
  out[(size_t)node * 128 + c] = r;
  hb[(size_t)node * 128 + c] = (unsigned short)f2bf(r);
}

// ---------------- Layers 2-4: bf16 gather-sum (fp32 accumulate) ----------------
// 16 lanes per dst row, uint4/lane (8 bf16 = 16B) => 256B/row coalesced.
// 4 nodes per wave; unroll 4 => 4 uint4 in flight per lane.
#define AGG_ACC(U)                                                    \
  a0.x += BLO((U).x); a0.y += BHI((U).x);                             \
  a0.z += BLO((U).y); a0.w += BHI((U).y);                             \
  a1.x += BLO((U).z); a1.y += BHI((U).z);                             \
  a1.z += BLO((U).w); a1.w += BHI((U).w);

__global__ __launch_bounds__(256) void k_agg_bf(const unsigned short* __restrict__ hb,
                                                const int* __restrict__ rowptr, const int* __restrict__ csr,
                                                float* __restrict__ aggout) {
  int node = (blockIdx.x * 256 + threadIdx.x) >> 4;
  int l = threadIdx.x & 15;
  if (node >= N_NODES) return;
  int s = rowptr[node], e = rowptr[node + 1];
  float4 a0 = make_float4(0.f, 0.f, 0.f, 0.f);
  float4 a1 = make_float4(0.f, 0.f, 0.f, 0.f);
  int p = s;
  for (; p + 4 <= e; p += 4) {
    int s0 = csr[p], s1 = csr[p + 1], s2 = csr[p + 2], s3 = csr[p + 3];
    uint4 u0 = *(const uint4*)&hb[(size_t)s0 * 128 + l * 8];
    uint4 u1 = *(const uint4*)&hb[(size_t)s1 * 128 + l * 8];
    uint4 u2 = *(const uint4*)&hb[(size_t)s2 * 128 + l * 8];
    uint4 u3 = *(const uint4*)&hb[(size_t)s3 * 128 + l * 8];
    AGG_ACC(u0)
    AGG_ACC(u1)
    AGG_ACC(u2)
    AGG_ACC(u3)
  }
  for (; p < e; ++p) {
    int s0 = csr[p];
    uint4 u = *(const uint4*)&hb[(size_t)s0 * 128 + l * 8];
    AGG_ACC(u)
  }
  *(float4*)&aggout[(size_t)node * 128 + l * 8] = a0;
  *(float4*)&aggout[(size_t)node * 128 + l * 8 + 4] = a1;
}

// ---------------- Layers 2-4: fused dual GEMM + bias + ReLU (+bf16 emit) ----
// out = relu(agg @ w_rel + h @ w_root + bias). 128x128 tile, 256 threads,
// 8x8 per thread, K-chunk 32, LDS 32 KB. All inner-loop math via explicit
// .xyzw components (no address-taken locals / runtime-indexed arrays).
#define GEMM_STEP(AV, M)                                                                   \
  acc[M][0].x += (AV)*b0.x; acc[M][0].y += (AV)*b0.y;                                      \
  acc[M][0].z += (AV)*b0.z; acc[M][0].w += (AV)*b0.w;                                      \
  acc[M][1].x += (AV)*b1.x; acc[M][1].y += (AV)*b1.y;                                      \
  acc[M][1].z += (AV)*b1.z; acc[M][1].w += (AV)*b1.w;

__global__ __launch_bounds__(256) void k_gemm4(const float* __restrict__ agg, const float* __restrict__ h,
                                               const float* __restrict__ w_rel, const float* __restrict__ w_root,
                                               const float* __restrict__ bias, float* __restrict__ out,
                                               unsigned short* __restrict__ hb) {
  __shared__ float AsT[32][128];
  __shared__ float Bs[32][128];
  const int n0 = blockIdx.x * 128;
  const int tid = threadIdx.x;
  const int tr = tid >> 4;  // 0..15 -> rows tr*8..tr*8+7
  const int tc = tid & 15;  // 0..15 -> cols 4tc..4tc+3, 64+4tc..64+4tc+3
  float4 acc[8][2];
#pragma unroll
  for (int m = 0; m < 8; ++m) {
    acc[m][0] = make_float4(0.f, 0.f, 0.f, 0.f);
    acc[m][1] = make_float4(0.f, 0.f, 0.f, 0.f);
  }

  for (int chunk = 0; chunk < 2; ++chunk) {
    const float* src = (chunk == 0) ? agg : h;
    const float* wgt = (chunk == 0) ? w_rel : w_root;
    for (int k0 = 0; k0 < 128; k0 += 32) {
      // stage A transposed: 128 rows x 32 k (1024 float4s, 4 per thread)
#pragma unroll
      for (int t = 0; t < 4; ++t) {
        int idx = tid + t * 256;
        int r = idx & 127, q = idx >> 7;  // q = 0..7
        int gr = n0 + r;
        if (gr >= N_NODES) gr = N_NODES - 1;
        float4 v = *(const float4*)&src[(size_t)gr * 128 + k0 + q * 4];
        AsT[q * 4 + 0][r] = v.x;
        AsT[q * 4 + 1][r] = v.y;
        AsT[q * 4 + 2][r] = v.z;
        AsT[q * 4 + 3][r] = v.w;
      }
      // stage B: 32 k x 128 c
#pragma unroll
      for (int t = 0; t < 4; ++t) {
        int idx = tid + t * 256;
        int k = idx >> 5, cq = idx & 31;
        *(float4*)&Bs[k][cq * 4] = *(const float4*)&wgt[(size_t)(k0 + k) * 128 + cq * 4];
      }
      __syncthreads();
#pragma unroll 4
      for (int k = 0; k < 32; ++k) {
        float4 a0 = *(float4*)&AsT[k][tr * 8];
        float4 a1 = *(float4*)&AsT[k][tr * 8 + 4];
        float4 b0 = *(float4*)&Bs[k][tc * 4];
        float4 b1 = *(float4*)&Bs[k][tc * 4 + 64];
        GEMM_STEP(a0.x, 0)
        GEMM_STEP(a0.y, 1)
        GEMM_STEP(a0.z, 2)
        GEMM_STEP(a0.w, 3)
        GEMM_STEP(a1.x, 4)
        GEMM_STEP(a1.y, 5)
        GEMM_STEP(a1.z, 6)
        GEMM_STEP(a1.w, 7)
      }
      __syncthreads();
    }
  }

  float4 bi0 = *(const float4*)&bias[tc * 4];
  float4 bi1 = *(const float4*)&bias[tc * 4 + 64];
#pragma unroll
  for (int m = 0; m < 8; ++m) {
    int row = n0 + tr * 8 + m;
    if (row < N_NODES) {
      float4 o0, o1;
      o0.x = fmaxf(acc[m][0].x + bi0.x, 0.f);
      o0.y = fmaxf(acc[m][0].y + bi0.y, 0.f);
      o0.z = fmaxf(acc[m][0].z + bi0.z, 0.f);
      o0.w = fmaxf(acc[m][0].w + bi0.w, 0.f);
      o1.x = fmaxf(acc[m][1].x + bi1.x, 0.f);
      o1.y = fmaxf(acc[m][1].y + bi1.y, 0.f);
      o1.z = fmaxf(acc[m][1].z + bi1.z, 0.f);
      o1.w = fmaxf(acc[m][1].w + bi1.w, 0.f);
      *(float4*)&out[(size_t)row * 128 + tc * 4] = o0;
      *(float4*)&out[(size_t)row * 128 + tc * 4 + 64] = o1;
      // bf16 shadow copy (gather source for next layer)
      uint2 pA, pB;
      pA.x = f2bf(o0.x) | (f2bf(o0.y) << 16);
      pA.y = f2bf(o0.z) | (f2bf(o0.w) << 16);
      pB.x = f2bf(o1.x) | (f2bf(o1.y) << 16);
      pB.y = f2bf(o1.z) | (f2bf(o1.w) << 16);
      *(uint2*)&hb[(size_t)row * 128 + tc * 4] = pA;
      *(uint2*)&hb[(size_t)row * 128 + tc * 4 + 64] = pB;
    }
  }
}

// ---------------- Pooling ----------------

__device__ __forceinline__ int lower_bound_batch(const int* __restrict__ batch, int key) {
  int lo = 0, hi = N_NODES;
  while (lo < hi) {
    int mid = (lo + hi) >> 1;
    if (batch[mid] < key) lo = mid + 1;
    else hi = mid;
  }
  return lo;
}

__global__ __launch_bounds__(256) void k_pool1(const float* __restrict__ h, const int* __restrict__ batch,
                                               float* __restrict__ psum, float* __restrict__ pmax) {
  int b = blockIdx.x;
  int g = b >> 2, q = b & 3;
  int start = lower_bound_batch(batch, g);
  int end = lower_bound_batch(batch, g + 1);
  int c = threadIdx.x & 127;
  int half = threadIdx.x >> 7;
  float sum = 0.f, mx = -3.0e38f;
  for (int n = start + q * 2 + half; n < end; n += 8) {
    float v = h[(size_t)n * 128 + c];
    sum += v;
    mx = fmaxf(mx, v);
  }
  __shared__ float ss[128], sm[128];
  if (half == 0) { ss[c] = sum; sm[c] = mx; }
  __syncthreads();
  if (half == 1) { ss[c] += sum; sm[c] = fmaxf(sm[c], mx); }
  __syncthreads();
  if (half == 0) {
    psum[(size_t)b * 128 + c] = ss[c];
    pmax[(size_t)b * 128 + c] = sm[c];
  }
}

__global__ __launch_bounds__(128) void k_pool2(const float* __restrict__ psum, const float* __restrict__ pmax,
                                               const int* __restrict__ batch, float* __restrict__ pooled) {
  int g = blockIdx.x;
  int c = threadIdx.x;
  int start = lower_bound_batch(batch, g), end = lower_bound_batch(batch, g + 1);
  int count = end - start;
  float s = 0.f, m = -3.0e38f;
#pragma unroll
  for (int q = 0; q < 4; ++q) {
    s += psum[(size_t)(g * 4 + q) * 128 + c];
    m = fmaxf(m, pmax[(size_t)(g * 4 + q) * 128 + c]);
  }
  pooled[(size_t)g * 256 + c] = (count > 0) ? m : 0.f;
  pooled[(size_t)g * 256 + 128 + c] = s / fmaxf((float)count, 1.f);
}

// ---------------- Final FC (fused metadata branch) ----------------

__global__ __launch_bounds__(128) void k_fc(const float* __restrict__ pooled, const float* __restrict__ metadata,
                                            const float* __restrict__ convm_w, const float* __restrict__ convm_b,
                                            const float* __restrict__ fc_w, const float* __restrict__ fc_b,
                                            const float* __restrict__ fc2_w, const float* __restrict__ fc2_b,
                                            float* __restrict__ out) {
  int g = blockIdx.x;
  int tid = threadIdx.x;
  __shared__ float xc[260];
  xc[tid] = pooled[(size_t)g * 256 + tid];
  xc[128 + tid] = pooled[(size_t)g * 256 + 128 + tid];
  if (tid < 4) xc[256 + tid] = fmaxf(metadata[g] * convm_w[tid] + convm_b[tid], 0.f);
  __syncthreads();
  float acc = fc_b[tid];
  for (int k = 0; k < 260; ++k) acc += xc[k] * fc_w[(size_t)k * 128 + tid];
  float partial = fmaxf(acc, 0.f) * fc2_w[tid];
#pragma unroll
  for (int off = 32; off > 0; off >>= 1) partial += __shfl_down(partial, off);
  __shared__ float wred[2];
  if ((tid & 63) == 0) wred[tid >> 6] = partial;
  __syncthreads();
  if (tid == 0) out[g] = wred[0] + wred[1] + fc2_b[0];
}

// ---------------- launch ----------------

extern "C" void kernel_launch(void* const* d_in, const int* in_sizes, int n_in,
                              void* d_out, int out_size, void* d_ws, size_t ws_size,
                              hipStream_t stream) {
  const float* x = (const float*)d_in[0];
  const float* metadata = (const float*)d_in[1];
  const int* ei = (const int*)d_in[2];
  const int* batch = (const int*)d_in[3];
  const float* w_rel[4] = {(const float*)d_in[4], (const float*)d_in[7], (const float*)d_in[10], (const float*)d_in[13]};
  const float* b_rel[4] = {(const float*)d_in[5], (const float*)d_in[8], (const float*)d_in[11], (const float*)d_in[14]};
  const float* w_root[4] = {(const float*)d_in[6], (const float*)d_in[9], (const float*)d_in[12], (const float*)d_in[15]};
  const float* convm_w = (const float*)d_in[16];
  const float* convm_b = (const float*)d_in[17];
  const float* fc_w = (const float*)d_in[18];
  const float* fc_b = (const float*)d_in[19];
  const float* fc2_w = (const float*)d_in[20];
  const float* fc2_b = (const float*)d_in[21];
  float* out = (float*)d_out;

  char* ws = (char*)d_ws;
  size_t off = 0;
  auto alloc = [&](size_t bytes) {
    off = (off + 255) & ~(size_t)255;
    void* p = ws + off;
    off += bytes;
    return p;
  };
  int* deg = (int*)alloc((size_t)N_NODES * 4);
  int* rowptr = (int*)alloc((size_t)(N_NODES + 1) * 4);
  int* cursor = (int*)alloc((size_t)N_NODES * 4);
  int* bsum = (int*)alloc(512 * 4);
  int* boff = (int*)alloc(512 * 4);
  int* csr = (int*)alloc((size_t)N_EDGES * 4);
  float* agg4 = (float*)alloc((size_t)N_NODES * 4 * 4);
  float* bufA = (float*)alloc((size_t)N_NODES * 128 * 4);           // h fp32 (in-place updated)
  float* bufB = (float*)alloc((size_t)N_NODES * 128 * 4);           // agg scratch fp32
  unsigned short* hb = (unsigned short*)alloc((size_t)N_NODES * 128 * 2);  // h bf16 shadow
  float* psum = (float*)alloc((size_t)256 * 128 * 4);
  float* pmax = (float*)alloc((size_t)256 * 128 * 4);
  float* pooled = (float*)alloc((size_t)64 * 256 * 4);

  const int nblk_nodes = (N_NODES + 255) / 256;
  const int nblk_edges = (N_EDGES + 255) / 256;

  // CSR build
  k_zero_int<<<nblk_nodes, 256, 0, stream>>>(deg, N_NODES);
  k_hist<<<nblk_edges, 256, 0, stream>>>(ei, deg);
  k_scan1<<<nblk_nodes, 256, 0, stream>>>(deg, rowptr, bsum);
  k_scan2<<<1, 512, 0, stream>>>(bsum, boff, nblk_nodes);
  k_scan3<<<(N_NODES + 1 + 255) / 256, 256, 0, stream>>>(rowptr, boff, rowptr, cursor);
  k_fill_win<<<8 * 128, 256, 0, stream>>>(ei, cursor, csr);

  // Layer 1
  k_l1_agg<<<(N_NODES * 4 + 255) / 256, 256, 0, stream>>>(x, rowptr, csr, agg4);
  k_l1_comb<<<(N_NODES * 128 + 255) / 256, 256, 0, stream>>>(x, agg4, w_rel[0], b_rel[0], w_root[0], bufA, hb);

  // Layers 2-4: bf16 gather (hb -> bufB), fused GEMM (bufB,bufA -> bufA + hb)
  for (int l = 1; l < 4; ++l) {
    k_agg_bf<<<(N_NODES * 16 + 255) / 256, 256, 0, stream>>>(hb, rowptr, csr, bufB);
    k_gemm4<<<(N_NODES + 127) / 128, 256, 0, stream>>>(bufB, bufA, w_rel[l], w_root[l], b_rel[l], bufA, hb);
  }

  // Pool + FC
  k_pool1<<<256, 256, 0, stream>>>(bufA, batch, psum, pmax);
  k_pool2<<<64, 128, 0, stream>>>(psum, pmax, batch, pooled);
  k_fc<<<64, 128, 0, stream>>>(pooled, metadata, convm_w, convm_b, fc_w, fc_b, fc2_w, fc2_b, out);
}